// Round 6
// baseline (113.027 us; speedup 1.0000x reference)
//
#include <hip/hip_runtime.h>

// out[n,m] = exp(-0.5 * sum_d (x[n,d]-c[m,d])^2 / s2[m,d]) / sqrt((2pi)^D * prod s2)
// Fast path (d-uniform variance per center; true for bench sigma==1):
//   out = exp2( L2E*(x.A) + qc*r2[n] + c0 ),  A = c/s2,  qc = -0.5*L2E/s2,
//   c0 = -0.5*L2E*(c.A) - 0.5*(D*log2(2pi) + sum log2 s2),  r2[n] = sum x^2
//
// Round 6: STORE WIDTH. R1-R5 all emitted global_store_dword (4 B/lane) and all
// plateaued at ~2.4 TB/s effective; the harness fills hit 6.1 TB/s with
// dwordx4. Each thread now owns 4 consecutive m (m=4*tid; block spans all M)
// and writes ONE plain global_store_dwordx4 per row. Also amortizes the LDS
// x-broadcast over 4x outputs and cuts epilogue/store instruction count 4x.

#define N_   16384
#define M_   1024
#define D_   32
#define NT   16      // rows per block -> grid 1024 blocks = 4/CU
#define BLK  256     // threads; thread t owns m in [4t, 4t+4)

typedef float v2f __attribute__((ext_vector_type(2)));
typedef float v4f __attribute__((ext_vector_type(4)));

__global__ __launch_bounds__(BLK, 3) void rbf_kernel(
    const float* __restrict__ x, const float* __restrict__ centers,
    const float* __restrict__ sigma, float* __restrict__ out)
{
    const int tid = threadIdx.x;
    const int n0  = blockIdx.x * NT;
    const int m0  = tid * 4;

    __shared__ float xs[NT * D_];   // 2 KB x tile
    __shared__ float r2s[NT];

    // stage x tile (coalesced) + r2 per row (8-lane shuffle reduce)
    if (tid < NT * D_ / 4) {        // 128 threads = waves 0,1 fully active
        const float4* xg = (const float4*)(x + (size_t)n0 * D_);
        float4 v = xg[tid];
        ((float4*)xs)[tid] = v;
        float s = fmaf(v.x, v.x, fmaf(v.y, v.y, fmaf(v.z, v.z, v.w * v.w)));
        s += __shfl_xor(s, 1);
        s += __shfl_xor(s, 2);
        s += __shfl_xor(s, 4);
        if ((tid & 7) == 0) r2s[tid >> 3] = s;
    }
    __syncthreads();

    const float L2E      = 1.4426950408889634f;   // log2(e)
    const float LOG2_2PI = 2.6514961294723187f;   // log2(2*pi)

    // sigma scan for this thread's 4 centers: d-uniform check + log-det
    float s2h[4], ldh[4];
    bool uf = true;
    {
        const float* sg = sigma + (size_t)m0 * D_;
        #pragma unroll
        for (int h = 0; h < 4; ++h) {
            float ld = 0.f, s20 = 0.f;
            bool u = true;
            #pragma unroll
            for (int d = 0; d < D_; ++d) {
                float s  = sg[h * D_ + d];
                float s2 = s * s;
                if (d == 0) s20 = s2;
                u = u && (s2 == s20);
                ld += log2f(s2);            // exactly 0 for sigma==1
            }
            s2h[h] = s20; ldh[h] = ld;
            uf = uf && u;
        }
    }

    if (__all((int)uf)) {
        v4f  A[4][8];                       // 128 VGPRs: 4 centers x 32 coeffs
        float c0[4], qc[4];
        {
            const v4f* cg = (const v4f*)(centers + (size_t)m0 * D_);
            #pragma unroll
            for (int h = 0; h < 4; ++h) {
                float w0 = 1.0f / s2h[h];
                float b  = 0.f;
                #pragma unroll
                for (int k = 0; k < 8; ++k) {
                    v4f c = cg[h * 8 + k];
                    v4f a = c * w0;
                    A[h][k] = a;
                    b = fmaf(c.x, a.x, fmaf(c.y, a.y, fmaf(c.z, a.z, fmaf(c.w, a.w, b))));
                }
                c0[h] = fmaf(-0.5f * L2E, b, -0.5f * (D_ * LOG2_2PI + ldh[h]));
                qc[h] = -0.5f * L2E * w0;
            }
        }
        // register barrier: A must stay VGPR-resident (R4 lesson)
        #pragma unroll
        for (int h = 0; h < 4; ++h)
            #pragma unroll
            for (int k = 0; k < 8; ++k)
                asm volatile("" : "+v"(A[h][k]));

        v4f* o = (v4f*)(out + (size_t)n0 * M_ + m0);
        #pragma unroll 1
        for (int i = 0; i < NT; ++i) {
            const v4f* xr = (const v4f*)(xs + i * D_);   // wave-uniform broadcast
            v2f a0 = {0,0}, a1 = {0,0}, a2 = {0,0}, a3 = {0,0};
            #pragma unroll
            for (int k = 0; k < 8; ++k) {
                v4f xv  = xr[k];                          // ds_read_b128
                v2f xlo = {xv.x, xv.y}, xhi = {xv.z, xv.w};
                v2f l0 = {A[0][k].x, A[0][k].y}, h0 = {A[0][k].z, A[0][k].w};
                v2f l1 = {A[1][k].x, A[1][k].y}, h1 = {A[1][k].z, A[1][k].w};
                v2f l2 = {A[2][k].x, A[2][k].y}, h2 = {A[2][k].z, A[2][k].w};
                v2f l3 = {A[3][k].x, A[3][k].y}, h3 = {A[3][k].z, A[3][k].w};
                a0 += xlo * l0; a0 += xhi * h0;           // v_pk_fma_f32
                a1 += xlo * l1; a1 += xhi * h1;
                a2 += xlo * l2; a2 += xhi * h2;
                a3 += xlo * l3; a3 += xhi * h3;
            }
            float r2 = r2s[i];
            v4f e;
            e.x = __builtin_amdgcn_exp2f(fmaf(L2E, a0.x + a0.y, fmaf(qc[0], r2, c0[0])));
            e.y = __builtin_amdgcn_exp2f(fmaf(L2E, a1.x + a1.y, fmaf(qc[1], r2, c0[1])));
            e.z = __builtin_amdgcn_exp2f(fmaf(L2E, a2.x + a2.y, fmaf(qc[2], r2, c0[2])));
            e.w = __builtin_amdgcn_exp2f(fmaf(L2E, a3.x + a3.y, fmaf(qc[3], r2, c0[3])));
            o[i * (M_ / 4)] = e;                          // global_store_dwordx4
        }
    } else {
        // general path: arbitrary per-d sigma, correct, not perf-tuned
        #pragma unroll 1
        for (int h = 0; h < 4; ++h) {
            const int m = m0 + h;
            const float* cg = centers + (size_t)m * D_;
            const float* sg = sigma   + (size_t)m * D_;
            const float c0 = -0.5f * (D_ * LOG2_2PI + ldh[h]);
            #pragma unroll 1
            for (int i = 0; i < NT; ++i) {
                const float* xr = xs + i * D_;
                float b0 = 0.f, b1 = 0.f;
                #pragma unroll
                for (int d = 0; d < D_; d += 2) {
                    float s0 = sg[d], s1 = sg[d + 1];
                    float t0 = xr[d]     - cg[d];
                    float t1 = xr[d + 1] - cg[d + 1];
                    b0 = fmaf(t0 * (1.0f / (s0 * s0)), t0, b0);
                    b1 = fmaf(t1 * (1.0f / (s1 * s1)), t1, b1);
                }
                float f = fmaf(-0.5f * L2E, b0 + b1, c0);
                out[(size_t)(n0 + i) * M_ + m] = __builtin_amdgcn_exp2f(f);
            }
        }
    }
}

extern "C" void kernel_launch(void* const* d_in, const int* in_sizes, int n_in,
                              void* d_out, int out_size, void* d_ws, size_t ws_size,
                              hipStream_t stream) {
    const float* x = (const float*)d_in[0];
    const float* c = (const float*)d_in[1];
    const float* s = (const float*)d_in[2];
    float* out = (float*)d_out;
    rbf_kernel<<<dim3(N_ / NT), BLK, 0, stream>>>(x, c, s, out);
}